// Round 10
// baseline (7160.712 us; speedup 1.0000x reference)
//
#include <hip/hip_runtime.h>
#include <hip/hip_bf16.h>

#define MM 8192
#define NN 11008
#define KK 4096
#define PKW 2048    // packed int32 words per output row

#define BM 256
#define BN 256
#define BKI 64                  // K per tile (i8)
#define NTI (KK / BKI)          // 64 K-tiles

typedef __attribute__((ext_vector_type(4)))  float f32x4;
typedef __attribute__((ext_vector_type(4)))  int   i32x4;
typedef __attribute__((ext_vector_type(16))) int   i32x16;
typedef __attribute__((ext_vector_type(8)))  short s16x8;
typedef __attribute__((ext_vector_type(4)))  short s16x4;

typedef __attribute__((address_space(3))) unsigned char        lds_u8;
typedef const __attribute__((address_space(1))) unsigned char  glb_u8;

static __device__ __forceinline__ unsigned short f2bf(float f) {
  union { float f; unsigned int u; } v; v.f = f;
  unsigned int u = v.u;
  u += 0x7fffu + ((u >> 16) & 1u);   // RNE
  return (unsigned short)(u >> 16);
}

// ---------------- quantize x: per-row absmax -> i8, PLAIN row-major ----------------

__global__ __launch_bounds__(256) void int4lin_quant_x(
    const float* __restrict__ X, signed char* __restrict__ O, float* __restrict__ xs)
{
  const int row  = blockIdx.x;
  const int t    = threadIdx.x;
  const int lane = t & 63;
  const int wave = t >> 6;
  const float* xr = X + (size_t)row * KK;

  f32x4 v[4];
  float mx = 0.0f;
#pragma unroll
  for (int j = 0; j < 4; ++j) {
    v[j] = *(const f32x4*)(xr + t * 16 + j * 4);
#pragma unroll
    for (int e = 0; e < 4; ++e) mx = fmaxf(mx, fabsf(v[j][e]));
  }
#pragma unroll
  for (int off = 32; off; off >>= 1) mx = fmaxf(mx, __shfl_xor(mx, off));
  __shared__ float red[4];
  if (lane == 0) red[wave] = mx;
  __syncthreads();
  mx = fmaxf(fmaxf(red[0], red[1]), fmaxf(red[2], red[3]));
  mx = fmaxf(mx, 1e-30f);
  const float rs = 127.0f / mx;
  if (t == 0) xs[row] = mx / 127.0f;

  i32x4 o;
#pragma unroll
  for (int w = 0; w < 4; ++w) {
    int acc = 0;
#pragma unroll
    for (int e = 0; e < 4; ++e) {
      int q = __float2int_rn(v[w][e] * rs);
      q = max(-127, min(127, q));
      acc |= (q & 0xff) << (8 * e);
    }
    o[w] = acc;
  }
  *(i32x4*)(O + (size_t)row * KK + t * 16) = o;
}

// ---------------- quantize w: nibbles -> i8 q in [-7,8], PLAIN row-major ----------------

__global__ void int4lin_quant_w(const int* __restrict__ P, signed char* __restrict__ O) {
  const int ntot = NN * 256;       // 16-byte output groups
  int i = blockIdx.x * blockDim.x + threadIdx.x;
  const int stride = gridDim.x * blockDim.x;
  for (; i < ntot; i += stride) {
    const int row = i >> 8;
    const int gr  = i & 255;
    const int* src = P + (size_t)row * PKW + gr * 8;   // 8 words -> 16 i8
    i32x4 va = *(const i32x4*)src;
    i32x4 vb = *(const i32x4*)(src + 4);
    i32x4 o;
#pragma unroll
    for (int h = 0; h < 2; ++h) {
      i32x4 w = h ? vb : va;
#pragma unroll
      for (int p = 0; p < 2; ++p) {
        const int b0 = w[2 * p], b1 = w[2 * p + 1];
        const int q0 = (b0 & 15) - 7, q1 = ((b0 >> 4) & 15) - 7;
        const int q2 = (b1 & 15) - 7, q3 = ((b1 >> 4) & 15) - 7;
        o[h * 2 + p] = (q0 & 0xff) | ((q1 & 0xff) << 8) | ((q2 & 0xff) << 16) | ((q3 & 0xff) << 24);
      }
    }
    *(i32x4*)(O + (size_t)row * KK + gr * 16) = o;
  }
}

// ---------------- 256x256x64 i8 GEMM, plane-major LDS, 2 blocks/CU ----------------
// LDS per buffer per operand: 16 KB = [4 k-planes][256 rows][16 B]; plane =
// ks*2+half. Fragment read (half-wave) = 512 CONTIGUOUS bytes -> conflict-free.
// Staging: global source is per-lane (plain row-major workspace); thread t of
// gload g covers (plane 2g+(t>>8), row t&255) -> LDS linear t*16. 4 gloads/tile.
// Sync: S1 = lgkmcnt(0)+barrier after frag reads (regs loaded; buffer free);
// stage t+2 into the freed buffer; MFMA; S2 = vmcnt(4)+barrier (t+1's 4 loads
// complete, t+2's 4 stay in flight).

__global__ __launch_bounds__(512, 4) void int4lin_gemm_i8(
    const signed char* __restrict__ Ai,   // M x K i8, row-major
    const signed char* __restrict__ Bi,   // N x K i8, row-major
    const float* __restrict__ xs,
    const float* __restrict__ scale,
    const float* __restrict__ bias,
    float* __restrict__ C)
{
  __shared__ signed char As[2][16384];   // 2 x 16 KiB
  __shared__ signed char Bs[2][16384];   // 2 x 16 KiB -> 64 KiB total

  const int tid  = threadIdx.x;
  const int lane = tid & 63;
  const int wave = tid >> 6;
  const int wm = wave >> 2;          // 0..1
  const int wn = wave & 3;           // 0..3

  // T1: bijective XCD swizzle (1376 = 8*172)
  const int bid = blockIdx.x;
  const int swz = (bid & 7) * 172 + (bid >> 3);
  const int bm = swz / 43;
  const int bn = swz - bm * 43;
  const size_t m0 = (size_t)bm * BM;
  const size_t n0 = (size_t)bn * BN;

  const int r5   = lane & 31;        // frag row/col within 32
  const int half = lane >> 5;        // k-half (16 i8) within instruction

  i32x16 acc[4][2] = {};             // [mf][nf]

  // LDS byte offsets: plane*(4096) + row*16; half folded into plane base
  const int aoff0 = half * 4096 + (wm * 128 + r5) * 16;   // + ks*8192 + mf*512
  const int boff0 = half * 4096 + (wn * 64 + r5) * 16;    // + ks*8192 + nf*512

#define LDA(buf, mf, ks) (*(const i32x4*)(&As[buf][aoff0 + (ks) * 8192 + (mf) * 512]))
#define LDB(buf, nf, ks) (*(const i32x4*)(&Bs[buf][boff0 + (ks) * 8192 + (nf) * 512]))

  const int srow   = tid & 255;        // staged row
  const int splane = tid >> 8;         // 0/1: plane within gload pair

  auto stage_a = [&](int buf, int kt, int g) {
    __builtin_amdgcn_global_load_lds(
        (glb_u8*)(Ai + (m0 + srow) * KK + kt + (2 * g + splane) * 16),
        (lds_u8*)(&As[buf][g * 8192 + tid * 16]), 16, 0, 0);
  };
  auto stage_b = [&](int buf, int kt, int g) {
    __builtin_amdgcn_global_load_lds(
        (glb_u8*)(Bi + (n0 + srow) * KK + kt + (2 * g + splane) * 16),
        (lds_u8*)(&Bs[buf][g * 8192 + tid * 16]), 16, 0, 0);
  };

  // -------- prologue: tile0 (4 loads) + tile1 (4 loads); wait tile0 --------
  stage_a(0, 0, 0); stage_a(0, 0, 1);
  stage_b(0, 0, 0); stage_b(0, 0, 1);
  stage_a(1, BKI, 0); stage_a(1, BKI, 1);
  stage_b(1, BKI, 0); stage_b(1, BKI, 1);
  asm volatile("s_waitcnt vmcnt(4)\n\ts_barrier" ::: "memory");

#pragma unroll 1
  for (int t = 0; t < NTI; ++t) {
    const int buf = t & 1;
    i32x4 a[4][2], b[2][2];

    // fragment reads (12 x b128, contiguous per half-wave)
#pragma unroll
    for (int ks = 0; ks < 2; ++ks) {
#pragma unroll
      for (int mf = 0; mf < 4; ++mf) a[mf][ks] = LDA(buf, mf, ks);
#pragma unroll
      for (int nf = 0; nf < 2; ++nf) b[nf][ks] = LDB(buf, nf, ks);
    }

    // S1: reads landed in regs; buffer is free for restage
    asm volatile("s_waitcnt lgkmcnt(0)\n\ts_barrier" ::: "memory");

    if (t + 2 < NTI) {
      stage_a(buf, (t + 2) * BKI, 0); stage_a(buf, (t + 2) * BKI, 1);
      stage_b(buf, (t + 2) * BKI, 0); stage_b(buf, (t + 2) * BKI, 1);
    }

    // MFMA 16 (all distinct accumulators within a ks-sweep)
    __builtin_amdgcn_s_setprio(1);
#pragma unroll
    for (int ks = 0; ks < 2; ++ks)
#pragma unroll
      for (int mf = 0; mf < 4; ++mf) {
        acc[mf][0] = __builtin_amdgcn_mfma_i32_32x32x32_i8(a[mf][ks], b[0][ks], acc[mf][0], 0, 0, 0);
        acc[mf][1] = __builtin_amdgcn_mfma_i32_32x32x32_i8(a[mf][ks], b[1][ks], acc[mf][1], 0, 0, 0);
      }
    __builtin_amdgcn_s_setprio(0);

    // S2: counted wait — tile t+1 ready, t+2's 4 loads stay in flight
    if (t < NTI - 2)       asm volatile("s_waitcnt vmcnt(4)\n\ts_barrier" ::: "memory");
    else if (t == NTI - 2) asm volatile("s_waitcnt vmcnt(0)\n\ts_barrier" ::: "memory");
    else                   asm volatile("s_barrier" ::: "memory");
  }

  // epilogue: y = acc * xs[row] * scale[col] + bias[col]
  // C/D 32x32: col = lane&31, row = (reg&3) + 8*(reg>>2) + 4*half
  const int colb = (int)n0 + wn * 64 + r5;
#pragma unroll
  for (int mf = 0; mf < 4; ++mf) {
    const size_t rbase = m0 + wm * 128 + mf * 32 + 4 * half;
#pragma unroll
    for (int reg = 0; reg < 16; ++reg) {
      const size_t row = rbase + (reg & 3) + 8 * (reg >> 2);
      const float xsr = xs[row];
      float* cp = C + row * NN + colb;
#pragma unroll
      for (int nf = 0; nf < 2; ++nf) {
        const int col = colb + nf * 32;
        cp[nf * 32] = (float)acc[mf][nf][reg] * xsr * scale[col] + bias[col];
      }
    }
  }
#undef LDA
#undef LDB
}

// ---------------- GEMM, inline-conversion bf16 fallback (no workspace needed) ----------------

__global__ __launch_bounds__(256) void int4lin_gemm_inline(
    const float* __restrict__ X,
    const int* __restrict__ P,
    const float* __restrict__ scale,
    const float* __restrict__ bias,
    float* __restrict__ C)
{
  __shared__ unsigned short As[128 * 64];
  __shared__ unsigned short Bs[128 * 64];

  const int tid  = threadIdx.x;
  const int lane = tid & 63;
  const int wave = tid >> 6;
  const int m0 = blockIdx.y * 128;
  const int n0 = blockIdx.x * 128;
  const int wr = (wave >> 1) * 64;
  const int wc = (wave & 1) * 64;

  f32x4 acc[4][4] = {};

  for (int kt = 0; kt < KK; kt += 64) {
#pragma unroll
    for (int i = 0; i < 8; ++i) {
      const int idx = i * 256 + tid;
      const int row = idx >> 4;
      const int c   = (idx & 15) << 2;
      f32x4 v = *(const f32x4*)(X + (size_t)(m0 + row) * KK + kt + c);
      s16x4 o;
      o[0] = (short)f2bf(v[0]); o[1] = (short)f2bf(v[1]);
      o[2] = (short)f2bf(v[2]); o[3] = (short)f2bf(v[3]);
      *(s16x4*)(As + row * 64 + (c ^ ((row & 7) << 3))) = o;
    }
#pragma unroll
    for (int i = 0; i < 4; ++i) {
      const int idx = i * 256 + tid;
      const int row = idx >> 3;
      const int c   = (idx & 7) << 3;
      i32x4 v = *(const i32x4*)(P + (size_t)(n0 + row) * PKW + ((kt + c) >> 1));
      s16x8 o;
#pragma unroll
      for (int j = 0; j < 4; ++j) {
        const int b = v[j];
        o[2 * j]     = (short)f2bf((float)((b & 15) - 7));
        o[2 * j + 1] = (short)f2bf((float)(((b >> 4) & 15) - 7));
      }
      *(s16x8*)(Bs + row * 64 + (c ^ ((row & 7) << 3))) = o;
    }
    __syncthreads();
#pragma unroll
    for (int kk = 0; kk < 2; ++kk) {
      const int rsel = lane & 15;
      const int ksel = ((((lane >> 4) << 3) + kk * 32)) ^ ((lane & 7) << 3);
      s16x8 af[4], bfr[4];
#pragma unroll
      for (int m = 0; m < 4; ++m)
        af[m] = *(const s16x8*)(As + (wr + m * 16 + rsel) * 64 + ksel);
#pragma unroll
      for (int n = 0; n < 4; ++n)
        bfr[n] = *(const s16x8*)(Bs + (wc + n * 16 + rsel) * 64 + ksel);
#pragma unroll
      for (int m = 0; m < 4; ++m)
#pragma unroll
        for (int n = 0; n < 4; ++n)
          acc[m][n] = __builtin_amdgcn_mfma_f32_16x16x32_bf16(af[m], bfr[n], acc[m][n], 0, 0, 0);
    }
    __syncthreads();
  }

  const int crow = wr + ((lane >> 4) << 2);
  const int ccol = wc + (lane & 15);
#pragma unroll
  for (int n = 0; n < 4; ++n) {
    const int gc = n0 + ccol + n * 16;
    const float sc = scale[gc];
    const float bi = bias[gc];
#pragma unroll
    for (int m = 0; m < 4; ++m) {
      float* cp = C + (size_t)(m0 + crow + m * 16) * NN + gc;
#pragma unroll
      for (int r = 0; r < 4; ++r)
        cp[(size_t)r * NN] = acc[m][n][r] * sc + bi;
    }
  }
}

// ---------------- launch ----------------

extern "C" void kernel_launch(void* const* d_in, const int* in_sizes, int n_in,
                              void* d_out, int out_size, void* d_ws, size_t ws_size,
                              hipStream_t stream) {
  const float* x      = (const float*)d_in[0];
  const int*   packed = (const int*)d_in[1];
  const float* scale  = (const float*)d_in[2];
  const float* bias   = (const float*)d_in[3];
  float* y = (float*)d_out;

  const size_t nXA = (size_t)MM * KK;                  // 32 MiB i8
  const size_t nWB = (size_t)NN * KK;                  // ~43 MiB i8
  const size_t nXS = (size_t)MM * sizeof(float);       // 32 KiB
  if (ws_size >= nXA + nWB + nXS) {
    signed char* xi = (signed char*)d_ws;
    signed char* wi = (signed char*)d_ws + nXA;
    float*       xsv = (float*)((char*)d_ws + nXA + nWB);
    int4lin_quant_x<<<MM, 256, 0, stream>>>(x, xi, xsv);
    int4lin_quant_w<<<2048, 256, 0, stream>>>(packed, wi);
    int4lin_gemm_i8<<<(NN / BN) * (MM / BM), 512, 0, stream>>>(xi, wi, xsv, scale, bias, y);
    return;
  }
  dim3 grid(NN / 128, MM / 128);
  int4lin_gemm_inline<<<grid, 256, 0, stream>>>(x, packed, scale, bias, y);
}

// Round 11
// 871.211 us; speedup vs baseline: 8.2193x; 8.2193x over previous
//
#include <hip/hip_runtime.h>
#include <hip/hip_bf16.h>

#define MM 8192
#define NN 11008
#define KK 4096
#define PKW 2048    // packed int32 words per output row

#define BM 128
#define BN 128
#define BKI 64                  // K per tile (i8)
#define NTI (KK / BKI)          // 64 K-tiles
#define NBM (MM / BM)           // 64
#define NBN (NN / BN)           // 86

typedef __attribute__((ext_vector_type(4)))  float f32x4;
typedef __attribute__((ext_vector_type(4)))  int   i32x4;
typedef __attribute__((ext_vector_type(16))) int   i32x16;
typedef __attribute__((ext_vector_type(8)))  short s16x8;
typedef __attribute__((ext_vector_type(4)))  short s16x4;

typedef __attribute__((address_space(3))) unsigned char        lds_u8;
typedef const __attribute__((address_space(1))) unsigned char  glb_u8;

static __device__ __forceinline__ unsigned short f2bf(float f) {
  union { float f; unsigned int u; } v; v.f = f;
  unsigned int u = v.u;
  u += 0x7fffu + ((u >> 16) & 1u);   // RNE
  return (unsigned short)(u >> 16);
}

// ---------------- quantize x: per-row absmax -> i8, PLAIN row-major ----------------

__global__ __launch_bounds__(256) void int4lin_quant_x(
    const float* __restrict__ X, signed char* __restrict__ O, float* __restrict__ xs)
{
  const int row  = blockIdx.x;
  const int t    = threadIdx.x;
  const int lane = t & 63;
  const int wave = t >> 6;
  const float* xr = X + (size_t)row * KK;

  f32x4 v[4];
  float mx = 0.0f;
#pragma unroll
  for (int j = 0; j < 4; ++j) {
    v[j] = *(const f32x4*)(xr + t * 16 + j * 4);
#pragma unroll
    for (int e = 0; e < 4; ++e) mx = fmaxf(mx, fabsf(v[j][e]));
  }
#pragma unroll
  for (int off = 32; off; off >>= 1) mx = fmaxf(mx, __shfl_xor(mx, off));
  __shared__ float red[4];
  if (lane == 0) red[wave] = mx;
  __syncthreads();
  mx = fmaxf(fmaxf(red[0], red[1]), fmaxf(red[2], red[3]));
  mx = fmaxf(mx, 1e-30f);
  const float rs = 127.0f / mx;
  if (t == 0) xs[row] = mx / 127.0f;

  i32x4 o;
#pragma unroll
  for (int w = 0; w < 4; ++w) {
    int acc = 0;
#pragma unroll
    for (int e = 0; e < 4; ++e) {
      int q = __float2int_rn(v[w][e] * rs);
      q = max(-127, min(127, q));
      acc |= (q & 0xff) << (8 * e);
    }
    o[w] = acc;
  }
  *(i32x4*)(O + (size_t)row * KK + t * 16) = o;
}

// ---------------- quantize w: nibbles -> i8 q in [-7,8], PLAIN row-major ----------------

__global__ void int4lin_quant_w(const int* __restrict__ P, signed char* __restrict__ O) {
  const int ntot = NN * 256;       // 16-byte output groups
  int i = blockIdx.x * blockDim.x + threadIdx.x;
  const int stride = gridDim.x * blockDim.x;
  for (; i < ntot; i += stride) {
    const int row = i >> 8;
    const int gr  = i & 255;
    const int* src = P + (size_t)row * PKW + gr * 8;   // 8 words -> 16 i8
    i32x4 va = *(const i32x4*)src;
    i32x4 vb = *(const i32x4*)(src + 4);
    i32x4 o;
#pragma unroll
    for (int h = 0; h < 2; ++h) {
      i32x4 w = h ? vb : va;
#pragma unroll
      for (int p = 0; p < 2; ++p) {
        const int b0 = w[2 * p], b1 = w[2 * p + 1];
        const int q0 = (b0 & 15) - 7, q1 = ((b0 >> 4) & 15) - 7;
        const int q2 = (b1 & 15) - 7, q3 = ((b1 >> 4) & 15) - 7;
        o[h * 2 + p] = (q0 & 0xff) | ((q1 & 0xff) << 8) | ((q2 & 0xff) << 16) | ((q3 & 0xff) << 24);
      }
    }
    *(i32x4*)(O + (size_t)row * KK + gr * 16) = o;
  }
}

// ---------------- 128x128x64 i8 GEMM, plane-major LDS, 3 blocks/CU ----------------
// 256 threads = 4 waves (2x2), per-wave 64x64 out = 4x i32x16 acc (64 AGPR).
// LDS per operand per buffer: 8 KB = [4 planes][128 rows][16 B], plane=ks*2+half.
// Half-wave fragment read = 512 contiguous bytes -> conflict-free (R10: 0 confl).
// Staging: 4 gloads/tile (A:2, B:2), per-lane global src (row-major workspace),
// linear LDS dst. Ring: stage t+2 after S1 frees the buffer. S2 vmcnt(4) leaves
// t+2's loads in flight (outstanding at S2(t) = t+1's 4 + t+2's 4 -> wait to 4).
// Occupancy: ~135 unified regs -> 3 waves/SIMD -> 3 independent blocks/CU;
// barriers stall one block, the other two keep MFMA/LDS/VMEM pipes fed.

__global__ __launch_bounds__(256, 3) void int4lin_gemm_i8(
    const signed char* __restrict__ Ai,   // M x K i8, row-major
    const signed char* __restrict__ Bi,   // N x K i8, row-major
    const float* __restrict__ xs,
    const float* __restrict__ scale,
    const float* __restrict__ bias,
    float* __restrict__ C)
{
  __shared__ signed char As[2][8192];   // 2 x 8 KiB
  __shared__ signed char Bs[2][8192];   // 2 x 8 KiB -> 32 KiB total

  const int tid  = threadIdx.x;
  const int lane = tid & 63;
  const int wave = tid >> 6;
  const int wm = wave >> 1;          // 0..1
  const int wn = wave & 1;           // 0..1

  // T1: bijective XCD swizzle (5504 = 8*688); consecutive swz share bm
  const int bid = blockIdx.x;
  const int swz = (bid & 7) * 688 + (bid >> 3);
  const int bm = swz / NBN;
  const int bn = swz - bm * NBN;
  const size_t m0 = (size_t)bm * BM;
  const size_t n0 = (size_t)bn * BN;

  const int r5   = lane & 31;        // frag row/col within 32
  const int half = lane >> 5;        // k-half (16 i8) within instruction

  i32x16 acc[2][2] = {};             // [mf][nf]

  // LDS byte offsets: plane*2048 + row*16; half folded into plane base
  const int aoff0 = half * 2048 + (wm * 64 + r5) * 16;   // + ks*4096 + mf*512
  const int boff0 = half * 2048 + (wn * 64 + r5) * 16;   // + ks*4096 + nf*512

#define LDA(buf, mf, ks) (*(const i32x4*)(&As[buf][aoff0 + (ks) * 4096 + (mf) * 512]))
#define LDB(buf, nf, ks) (*(const i32x4*)(&Bs[buf][boff0 + (ks) * 4096 + (nf) * 512]))

  const int srow   = tid & 127;        // staged row
  const int splane = tid >> 7;         // 0/1: plane within gload pair

  auto stage_a = [&](int buf, int kt, int g) {
    __builtin_amdgcn_global_load_lds(
        (glb_u8*)(Ai + (m0 + srow) * KK + kt + (2 * g + splane) * 16),
        (lds_u8*)(&As[buf][g * 4096 + tid * 16]), 16, 0, 0);
  };
  auto stage_b = [&](int buf, int kt, int g) {
    __builtin_amdgcn_global_load_lds(
        (glb_u8*)(Bi + (n0 + srow) * KK + kt + (2 * g + splane) * 16),
        (lds_u8*)(&Bs[buf][g * 4096 + tid * 16]), 16, 0, 0);
  };

  // -------- prologue: tile0 (4 loads) + tile1 (4 loads); wait tile0 --------
  stage_a(0, 0, 0); stage_a(0, 0, 1);
  stage_b(0, 0, 0); stage_b(0, 0, 1);
  stage_a(1, BKI, 0); stage_a(1, BKI, 1);
  stage_b(1, BKI, 0); stage_b(1, BKI, 1);
  asm volatile("s_waitcnt vmcnt(4)\n\ts_barrier" ::: "memory");

#pragma unroll 1
  for (int t = 0; t < NTI; ++t) {
    const int buf = t & 1;
    i32x4 a[2][2], b[2][2];

    // fragment reads (8 x b128, contiguous per half-wave)
#pragma unroll
    for (int ks = 0; ks < 2; ++ks) {
#pragma unroll
      for (int mf = 0; mf < 2; ++mf) a[mf][ks] = LDA(buf, mf, ks);
#pragma unroll
      for (int nf = 0; nf < 2; ++nf) b[nf][ks] = LDB(buf, nf, ks);
    }

    // S1: reads landed in regs; buffer free for restage
    asm volatile("s_waitcnt lgkmcnt(0)\n\ts_barrier" ::: "memory");

    if (t + 2 < NTI) {
      stage_a(buf, (t + 2) * BKI, 0); stage_a(buf, (t + 2) * BKI, 1);
      stage_b(buf, (t + 2) * BKI, 0); stage_b(buf, (t + 2) * BKI, 1);
    }

    // MFMA 8 (all distinct accumulators within a ks-sweep)
    __builtin_amdgcn_s_setprio(1);
#pragma unroll
    for (int ks = 0; ks < 2; ++ks)
#pragma unroll
      for (int mf = 0; mf < 2; ++mf) {
        acc[mf][0] = __builtin_amdgcn_mfma_i32_32x32x32_i8(a[mf][ks], b[0][ks], acc[mf][0], 0, 0, 0);
        acc[mf][1] = __builtin_amdgcn_mfma_i32_32x32x32_i8(a[mf][ks], b[1][ks], acc[mf][1], 0, 0, 0);
      }
    __builtin_amdgcn_s_setprio(0);

    // S2: counted wait — tile t+1 ready, t+2's 4 loads stay in flight
    if (t < NTI - 2)       asm volatile("s_waitcnt vmcnt(4)\n\ts_barrier" ::: "memory");
    else if (t == NTI - 2) asm volatile("s_waitcnt vmcnt(0)\n\ts_barrier" ::: "memory");
    else                   asm volatile("s_barrier" ::: "memory");
  }

  // epilogue: y = acc * xs[row] * scale[col] + bias[col]
  // C/D 32x32: col = lane&31, row = (reg&3) + 8*(reg>>2) + 4*half
  const int colb = (int)n0 + wn * 64 + r5;
#pragma unroll
  for (int mf = 0; mf < 2; ++mf) {
    const size_t rbase = m0 + wm * 64 + mf * 32 + 4 * half;
#pragma unroll
    for (int reg = 0; reg < 16; ++reg) {
      const size_t row = rbase + (reg & 3) + 8 * (reg >> 2);
      const float xsr = xs[row];
      float* cp = C + row * NN + colb;
#pragma unroll
      for (int nf = 0; nf < 2; ++nf) {
        const int col = colb + nf * 32;
        cp[nf * 32] = (float)acc[mf][nf][reg] * xsr * scale[col] + bias[col];
      }
    }
  }
#undef LDA
#undef LDB
}

// ---------------- GEMM, inline-conversion bf16 fallback (no workspace needed) ----------------

__global__ __launch_bounds__(256) void int4lin_gemm_inline(
    const float* __restrict__ X,
    const int* __restrict__ P,
    const float* __restrict__ scale,
    const float* __restrict__ bias,
    float* __restrict__ C)
{
  __shared__ unsigned short As[128 * 64];
  __shared__ unsigned short Bs[128 * 64];

  const int tid  = threadIdx.x;
  const int lane = tid & 63;
  const int wave = tid >> 6;
  const int m0 = blockIdx.y * 128;
  const int n0 = blockIdx.x * 128;
  const int wr = (wave >> 1) * 64;
  const int wc = (wave & 1) * 64;

  f32x4 acc[4][4] = {};

  for (int kt = 0; kt < KK; kt += 64) {
#pragma unroll
    for (int i = 0; i < 8; ++i) {
      const int idx = i * 256 + tid;
      const int row = idx >> 4;
      const int c   = (idx & 15) << 2;
      f32x4 v = *(const f32x4*)(X + (size_t)(m0 + row) * KK + kt + c);
      s16x4 o;
      o[0] = (short)f2bf(v[0]); o[1] = (short)f2bf(v[1]);
      o[2] = (short)f2bf(v[2]); o[3] = (short)f2bf(v[3]);
      *(s16x4*)(As + row * 64 + (c ^ ((row & 7) << 3))) = o;
    }
#pragma unroll
    for (int i = 0; i < 4; ++i) {
      const int idx = i * 256 + tid;
      const int row = idx >> 3;
      const int c   = (idx & 7) << 3;
      i32x4 v = *(const i32x4*)(P + (size_t)(n0 + row) * PKW + ((kt + c) >> 1));
      s16x8 o;
#pragma unroll
      for (int j = 0; j < 4; ++j) {
        const int b = v[j];
        o[2 * j]     = (short)f2bf((float)((b & 15) - 7));
        o[2 * j + 1] = (short)f2bf((float)(((b >> 4) & 15) - 7));
      }
      *(s16x8*)(Bs + row * 64 + (c ^ ((row & 7) << 3))) = o;
    }
    __syncthreads();
#pragma unroll
    for (int kk = 0; kk < 2; ++kk) {
      const int rsel = lane & 15;
      const int ksel = ((((lane >> 4) << 3) + kk * 32)) ^ ((lane & 7) << 3);
      s16x8 af[4], bfr[4];
#pragma unroll
      for (int m = 0; m < 4; ++m)
        af[m] = *(const s16x8*)(As + (wr + m * 16 + rsel) * 64 + ksel);
#pragma unroll
      for (int n = 0; n < 4; ++n)
        bfr[n] = *(const s16x8*)(Bs + (wc + n * 16 + rsel) * 64 + ksel);
#pragma unroll
      for (int m = 0; m < 4; ++m)
#pragma unroll
        for (int n = 0; n < 4; ++n)
          acc[m][n] = __builtin_amdgcn_mfma_f32_16x16x32_bf16(af[m], bfr[n], acc[m][n], 0, 0, 0);
    }
    __syncthreads();
  }

  const int crow = wr + ((lane >> 4) << 2);
  const int ccol = wc + (lane & 15);
#pragma unroll
  for (int n = 0; n < 4; ++n) {
    const int gc = n0 + ccol + n * 16;
    const float sc = scale[gc];
    const float bi = bias[gc];
#pragma unroll
    for (int m = 0; m < 4; ++m) {
      float* cp = C + (size_t)(m0 + crow + m * 16) * NN + gc;
#pragma unroll
      for (int r = 0; r < 4; ++r)
        cp[(size_t)r * NN] = acc[m][n][r] * sc + bi;
    }
  }
}

// ---------------- launch ----------------

extern "C" void kernel_launch(void* const* d_in, const int* in_sizes, int n_in,
                              void* d_out, int out_size, void* d_ws, size_t ws_size,
                              hipStream_t stream) {
  const float* x      = (const float*)d_in[0];
  const int*   packed = (const int*)d_in[1];
  const float* scale  = (const float*)d_in[2];
  const float* bias   = (const float*)d_in[3];
  float* y = (float*)d_out;

  const size_t nXA = (size_t)MM * KK;                  // 32 MiB i8
  const size_t nWB = (size_t)NN * KK;                  // ~43 MiB i8
  const size_t nXS = (size_t)MM * sizeof(float);       // 32 KiB
  if (ws_size >= nXA + nWB + nXS) {
    signed char* xi = (signed char*)d_ws;
    signed char* wi = (signed char*)d_ws + nXA;
    float*       xsv = (float*)((char*)d_ws + nXA + nWB);
    int4lin_quant_x<<<MM, 256, 0, stream>>>(x, xi, xsv);
    int4lin_quant_w<<<2048, 256, 0, stream>>>(packed, wi);
    int4lin_gemm_i8<<<NBM * NBN, 256, 0, stream>>>(xi, wi, xsv, scale, bias, y);
    return;
  }
  dim3 grid(NN / 128, MM / 128);
  int4lin_gemm_inline<<<grid, 256, 0, stream>>>(x, packed, scale, bias, y);
}

// Round 12
// 782.886 us; speedup vs baseline: 9.1466x; 1.1128x over previous
//
#include <hip/hip_runtime.h>
#include <hip/hip_bf16.h>

#define MM 8192
#define NN 11008
#define KK 4096
#define PKW 2048    // packed int32 words per output row

#define BM 256
#define BN 256
#define BKI 64                  // K per tile (i8)
#define NTI (KK / BKI)          // 64 K-tiles
#define NBM (MM / BM)           // 32
#define NBN (NN / BN)           // 43

typedef __attribute__((ext_vector_type(4)))  float f32x4;
typedef __attribute__((ext_vector_type(4)))  int   i32x4;
typedef __attribute__((ext_vector_type(16))) int   i32x16;
typedef __attribute__((ext_vector_type(8)))  short s16x8;
typedef __attribute__((ext_vector_type(4)))  short s16x4;

typedef __attribute__((address_space(3))) unsigned char        lds_u8;
typedef const __attribute__((address_space(1))) unsigned char  glb_u8;

static __device__ __forceinline__ unsigned short f2bf(float f) {
  union { float f; unsigned int u; } v; v.f = f;
  unsigned int u = v.u;
  u += 0x7fffu + ((u >> 16) & 1u);   // RNE
  return (unsigned short)(u >> 16);
}

// ---------------- quantize x: per-row absmax -> i8, PLAIN row-major ----------------

__global__ __launch_bounds__(256) void int4lin_quant_x(
    const float* __restrict__ X, signed char* __restrict__ O, float* __restrict__ xs)
{
  const int row  = blockIdx.x;
  const int t    = threadIdx.x;
  const int lane = t & 63;
  const int wave = t >> 6;
  const float* xr = X + (size_t)row * KK;

  f32x4 v[4];
  float mx = 0.0f;
#pragma unroll
  for (int j = 0; j < 4; ++j) {
    v[j] = *(const f32x4*)(xr + t * 16 + j * 4);
#pragma unroll
    for (int e = 0; e < 4; ++e) mx = fmaxf(mx, fabsf(v[j][e]));
  }
#pragma unroll
  for (int off = 32; off; off >>= 1) mx = fmaxf(mx, __shfl_xor(mx, off));
  __shared__ float red[4];
  if (lane == 0) red[wave] = mx;
  __syncthreads();
  mx = fmaxf(fmaxf(red[0], red[1]), fmaxf(red[2], red[3]));
  mx = fmaxf(mx, 1e-30f);
  const float rs = 127.0f / mx;
  if (t == 0) xs[row] = mx / 127.0f;

  i32x4 o;
#pragma unroll
  for (int w = 0; w < 4; ++w) {
    int acc = 0;
#pragma unroll
    for (int e = 0; e < 4; ++e) {
      int q = __float2int_rn(v[w][e] * rs);
      q = max(-127, min(127, q));
      acc |= (q & 0xff) << (8 * e);
    }
    o[w] = acc;
  }
  *(i32x4*)(O + (size_t)row * KK + t * 16) = o;
}

// ---------------- quantize w: nibbles -> i8 q in [-7,8], PLAIN row-major ----------------

__global__ void int4lin_quant_w(const int* __restrict__ P, signed char* __restrict__ O) {
  const int ntot = NN * 256;       // 16-byte output groups
  int i = blockIdx.x * blockDim.x + threadIdx.x;
  const int stride = gridDim.x * blockDim.x;
  for (; i < ntot; i += stride) {
    const int row = i >> 8;
    const int gr  = i & 255;
    const int* src = P + (size_t)row * PKW + gr * 8;   // 8 words -> 16 i8
    i32x4 va = *(const i32x4*)src;
    i32x4 vb = *(const i32x4*)(src + 4);
    i32x4 o;
#pragma unroll
    for (int h = 0; h < 2; ++h) {
      i32x4 w = h ? vb : va;
#pragma unroll
      for (int p = 0; p < 2; ++p) {
        const int b0 = w[2 * p], b1 = w[2 * p + 1];
        const int q0 = (b0 & 15) - 7, q1 = ((b0 >> 4) & 15) - 7;
        const int q2 = (b1 & 15) - 7, q3 = ((b1 >> 4) & 15) - 7;
        o[h * 2 + p] = (q0 & 0xff) | ((q1 & 0xff) << 8) | ((q2 & 0xff) << 16) | ((q3 & 0xff) << 24);
      }
    }
    *(i32x4*)(O + (size_t)row * KK + gr * 16) = o;
  }
}

// ---------------- 256x256x64 i8 GEMM, depth-3 ring, 1 barrier/tile ----------------
// 512 threads = 8 waves (2x4), per-wave 128x64 out = 8x i32x16 acc (128 AGPR).
// LDS: 4 buffers x (A 16KB + B 16KB) = 128 KB. Per buffer per operand:
// [4 planes][256 rows][16B], plane = ks*2+half -> half-wave fragment read =
// 512 contiguous bytes, conflict-free (R10/R11: 0 conflicts).
// Ring: at tile t stage tile t+3 into buf[(t+3)&3] (4 gloads: A x2, B x2).
// Safety: buf[(t+3)&3] last read at tile t-1; all waves passed S2(t-1) barrier
// before any stage of t -> no S1 needed, ONE barrier per tile.
// S2(t): vmcnt(8) = tiles t+2,t+3 (8 loads) stay in flight, t+1 complete.
// Issue-to-drain distance = 3 tiles (~5000 cyc) >> HBM latency.

__global__ __launch_bounds__(512, 2) void int4lin_gemm_i8(
    const signed char* __restrict__ Ai,   // M x K i8, row-major
    const signed char* __restrict__ Bi,   // N x K i8, row-major
    const float* __restrict__ xs,
    const float* __restrict__ scale,
    const float* __restrict__ bias,
    float* __restrict__ C)
{
  __shared__ signed char As[4][16384];   // 4 x 16 KiB
  __shared__ signed char Bs[4][16384];   // 4 x 16 KiB -> 128 KiB total

  const int tid  = threadIdx.x;
  const int lane = tid & 63;
  const int wave = tid >> 6;
  const int wm = wave >> 2;          // 0..1
  const int wn = wave & 3;           // 0..3

  // T1: bijective XCD swizzle (1376 = 8*172); consecutive swz share bm
  const int bid = blockIdx.x;
  const int swz = (bid & 7) * 172 + (bid >> 3);
  const int bm = swz / NBN;
  const int bn = swz - bm * NBN;
  const size_t m0 = (size_t)bm * BM;
  const size_t n0 = (size_t)bn * BN;

  const int r5   = lane & 31;        // frag row/col within 32
  const int half = lane >> 5;        // k-half (16 i8) within instruction

  i32x16 acc[4][2] = {};             // [mf][nf]

  // LDS byte offsets: plane*4096 + row*16; plane = ks*2+half
  const int aoff0 = half * 4096 + (wm * 128 + r5) * 16;   // + ks*8192 + mf*512
  const int boff0 = half * 4096 + (wn * 64 + r5) * 16;    // + ks*8192 + nf*512

#define LDA(buf, mf, ks) (*(const i32x4*)(&As[buf][aoff0 + (ks) * 8192 + (mf) * 512]))
#define LDB(buf, nf, ks) (*(const i32x4*)(&Bs[buf][boff0 + (ks) * 8192 + (nf) * 512]))

  const int srow   = tid & 255;        // staged row
  const int splane = tid >> 8;         // 0/1: plane within gload pair

  auto stage = [&](int buf, int kt) {
#pragma unroll
    for (int g = 0; g < 2; ++g)
      __builtin_amdgcn_global_load_lds(
          (glb_u8*)(Ai + (m0 + srow) * KK + kt + (2 * g + splane) * 16),
          (lds_u8*)(&As[buf][g * 8192 + tid * 16]), 16, 0, 0);
#pragma unroll
    for (int g = 0; g < 2; ++g)
      __builtin_amdgcn_global_load_lds(
          (glb_u8*)(Bi + (n0 + srow) * KK + kt + (2 * g + splane) * 16),
          (lds_u8*)(&Bs[buf][g * 8192 + tid * 16]), 16, 0, 0);
  };

  // -------- prologue: stage tiles 0,1,2 (12 loads); wait tile0 (8 left) --------
  stage(0, 0);
  stage(1, BKI);
  stage(2, 2 * BKI);
  asm volatile("s_waitcnt vmcnt(8)\n\ts_barrier" ::: "memory");

#pragma unroll 1
  for (int t = 0; t < NTI; ++t) {
    const int buf = t & 3;

    // stage tile t+3 into the buffer freed at S2(t-1)
    if (t + 3 < NTI) stage((t + 3) & 3, (t + 3) * BKI);

    // fragment reads (12 x b128, contiguous per half-wave)
    i32x4 a[4][2], b[2][2];
#pragma unroll
    for (int ks = 0; ks < 2; ++ks) {
#pragma unroll
      for (int mf = 0; mf < 4; ++mf) a[mf][ks] = LDA(buf, mf, ks);
#pragma unroll
      for (int nf = 0; nf < 2; ++nf) b[nf][ks] = LDB(buf, nf, ks);
    }

    // MFMA 16 (8 distinct accumulators per ks-sweep)
    __builtin_amdgcn_s_setprio(1);
#pragma unroll
    for (int ks = 0; ks < 2; ++ks)
#pragma unroll
      for (int mf = 0; mf < 4; ++mf) {
        acc[mf][0] = __builtin_amdgcn_mfma_i32_32x32x32_i8(a[mf][ks], b[0][ks], acc[mf][0], 0, 0, 0);
        acc[mf][1] = __builtin_amdgcn_mfma_i32_32x32x32_i8(a[mf][ks], b[1][ks], acc[mf][1], 0, 0, 0);
      }
    __builtin_amdgcn_s_setprio(0);

    // S2: counted wait — t+1 complete, t+2/t+3 (8 loads) stay in flight
    if (t < NTI - 3)       asm volatile("s_waitcnt vmcnt(8)\n\ts_barrier" ::: "memory");
    else if (t == NTI - 3) asm volatile("s_waitcnt vmcnt(4)\n\ts_barrier" ::: "memory");
    else if (t == NTI - 2) asm volatile("s_waitcnt vmcnt(0)\n\ts_barrier" ::: "memory");
    // t == NTI-1: fall through to epilogue
  }

  // epilogue: y = acc * xs[row] * scale[col] + bias[col]
  // C/D 32x32: col = lane&31, row = (reg&3) + 8*(reg>>2) + 4*half
  const int colb = (int)n0 + wn * 64 + r5;
#pragma unroll
  for (int mf = 0; mf < 4; ++mf) {
    const size_t rbase = m0 + wm * 128 + mf * 32 + 4 * half;
#pragma unroll
    for (int reg = 0; reg < 16; ++reg) {
      const size_t row = rbase + (reg & 3) + 8 * (reg >> 2);
      const float xsr = xs[row];
      float* cp = C + row * NN + colb;
#pragma unroll
      for (int nf = 0; nf < 2; ++nf) {
        const int col = colb + nf * 32;
        cp[nf * 32] = (float)acc[mf][nf][reg] * xsr * scale[col] + bias[col];
      }
    }
  }
#undef LDA
#undef LDB
}

// ---------------- GEMM, inline-conversion bf16 fallback (no workspace needed) ----------------

__global__ __launch_bounds__(256) void int4lin_gemm_inline(
    const float* __restrict__ X,
    const int* __restrict__ P,
    const float* __restrict__ scale,
    const float* __restrict__ bias,
    float* __restrict__ C)
{
  __shared__ unsigned short As[128 * 64];
  __shared__ unsigned short Bs[128 * 64];

  const int tid  = threadIdx.x;
  const int lane = tid & 63;
  const int wave = tid >> 6;
  const int m0 = blockIdx.y * 128;
  const int n0 = blockIdx.x * 128;
  const int wr = (wave >> 1) * 64;
  const int wc = (wave & 1) * 64;

  f32x4 acc[4][4] = {};

  for (int kt = 0; kt < KK; kt += 64) {
#pragma unroll
    for (int i = 0; i < 8; ++i) {
      const int idx = i * 256 + tid;
      const int row = idx >> 4;
      const int c   = (idx & 15) << 2;
      f32x4 v = *(const f32x4*)(X + (size_t)(m0 + row) * KK + kt + c);
      s16x4 o;
      o[0] = (short)f2bf(v[0]); o[1] = (short)f2bf(v[1]);
      o[2] = (short)f2bf(v[2]); o[3] = (short)f2bf(v[3]);
      *(s16x4*)(As + row * 64 + (c ^ ((row & 7) << 3))) = o;
    }
#pragma unroll
    for (int i = 0; i < 4; ++i) {
      const int idx = i * 256 + tid;
      const int row = idx >> 3;
      const int c   = (idx & 7) << 3;
      i32x4 v = *(const i32x4*)(P + (size_t)(n0 + row) * PKW + ((kt + c) >> 1));
      s16x8 o;
#pragma unroll
      for (int j = 0; j < 4; ++j) {
        const int b = v[j];
        o[2 * j]     = (short)f2bf((float)((b & 15) - 7));
        o[2 * j + 1] = (short)f2bf((float)(((b >> 4) & 15) - 7));
      }
      *(s16x8*)(Bs + row * 64 + (c ^ ((row & 7) << 3))) = o;
    }
    __syncthreads();
#pragma unroll
    for (int kk = 0; kk < 2; ++kk) {
      const int rsel = lane & 15;
      const int ksel = ((((lane >> 4) << 3) + kk * 32)) ^ ((lane & 7) << 3);
      s16x8 af[4], bfr[4];
#pragma unroll
      for (int m = 0; m < 4; ++m)
        af[m] = *(const s16x8*)(As + (wr + m * 16 + rsel) * 64 + ksel);
#pragma unroll
      for (int n = 0; n < 4; ++n)
        bfr[n] = *(const s16x8*)(Bs + (wc + n * 16 + rsel) * 64 + ksel);
#pragma unroll
      for (int m = 0; m < 4; ++m)
#pragma unroll
        for (int n = 0; n < 4; ++n)
          acc[m][n] = __builtin_amdgcn_mfma_f32_16x16x32_bf16(af[m], bfr[n], acc[m][n], 0, 0, 0);
    }
    __syncthreads();
  }

  const int crow = wr + ((lane >> 4) << 2);
  const int ccol = wc + (lane & 15);
#pragma unroll
  for (int n = 0; n < 4; ++n) {
    const int gc = n0 + ccol + n * 16;
    const float sc = scale[gc];
    const float bi = bias[gc];
#pragma unroll
    for (int m = 0; m < 4; ++m) {
      float* cp = C + (size_t)(m0 + crow + m * 16) * NN + gc;
#pragma unroll
      for (int r = 0; r < 4; ++r)
        cp[(size_t)r * NN] = acc[m][n][r] * sc + bi;
    }
  }
}

// ---------------- launch ----------------

extern "C" void kernel_launch(void* const* d_in, const int* in_sizes, int n_in,
                              void* d_out, int out_size, void* d_ws, size_t ws_size,
                              hipStream_t stream) {
  const float* x      = (const float*)d_in[0];
  const int*   packed = (const int*)d_in[1];
  const float* scale  = (const float*)d_in[2];
  const float* bias   = (const float*)d_in[3];
  float* y = (float*)d_out;

  const size_t nXA = (size_t)MM * KK;                  // 32 MiB i8
  const size_t nWB = (size_t)NN * KK;                  // ~43 MiB i8
  const size_t nXS = (size_t)MM * sizeof(float);       // 32 KiB
  if (ws_size >= nXA + nWB + nXS) {
    signed char* xi = (signed char*)d_ws;
    signed char* wi = (signed char*)d_ws + nXA;
    float*       xsv = (float*)((char*)d_ws + nXA + nWB);
    int4lin_quant_x<<<MM, 256, 0, stream>>>(x, xi, xsv);
    int4lin_quant_w<<<2048, 256, 0, stream>>>(packed, wi);
    int4lin_gemm_i8<<<NBM * NBN, 512, 0, stream>>>(xi, wi, xsv, scale, bias, y);
    return;
  }
  dim3 grid(NN / 128, MM / 128);
  int4lin_gemm_inline<<<grid, 256, 0, stream>>>(x, packed, scale, bias, y);
}